// Round 1
// baseline (139.784 us; speedup 1.0000x reference)
//
#include <hip/hip_runtime.h>

#define IN_FEATURES 212445
#define N1 65536
#define N2 16384
#define NCLS 20
#define BATCH 32
#define HIST_BLOCKS 32
#define MCHUNK 1024
#define MBLOCKS ((IN_FEATURES + MCHUNK - 1) / MCHUNK)   // 208
#define TOTF (BATCH * IN_FEATURES)                       // 6798240 (divisible by 4)
#define TOTF4 (TOTF / 4)                                 // 1699560
#define CF4 2048                                         // float4 per block (8192 elems)
#define NT3B ((TOTF4 + CF4 - 1) / CF4)                   // 830

// ws layout (bytes):
//  t3    : float[32*128]   @ 0      (16384) -- zeroed by k_setup block 0
//  hist  : int[32*256]     @ 16384  (32768) -- per-block partial counts
//  Sa    : float[20*128]   @ 49152  (10240) -- sum_o fc_w[cls,o*128+m]*u2[o]
//  Sv    : float[20*128]   @ 59392  (10240) -- ... *v2[o]
//  Sw    : float[20*128]   @ 69632  (10240) -- ... *w2[o]
//  Sb    : float[20*128]   @ 79872  (10240) -- ... *b2[o]
//  midx  : int[212445]     @ 90112  (849780) -- composed parent chain

// k_setup, grid = 1 + NCLS + HIST_BLOCKS + MBLOCKS = 261:
//  b=0        : zero t3
//  b=1..20    : per-class Sa/Sv/Sw/Sb (redundantly composes u2/v2/w2 from
//               W0..W2 per block -- 8K mults, trivial -- then contracts the
//               64KB fc_w row; runs concurrent with midx blocks)
//  b=21..52   : count histograms (c2 over N1 via chain, cnt2 over N2)
//  b=53..260  : midx[i] = p2[p1[p0[i]]]
__global__ __launch_bounds__(256) void k_setup(
    const float* __restrict__ W0, const float* __restrict__ b0,
    const float* __restrict__ W1, const float* __restrict__ b1,
    const float* __restrict__ W2, const float* __restrict__ b2,
    const float* __restrict__ fc_w,
    const int* __restrict__ p0, const int* __restrict__ p1,
    const int* __restrict__ p2,
    float* __restrict__ t3, int* __restrict__ hist,
    float* __restrict__ Sa, float* __restrict__ Sv,
    float* __restrict__ Sw, float* __restrict__ Sb,
    int* __restrict__ midx)
{
    int t = threadIdx.x;
    int b = blockIdx.x;
    if (b == 0) {
        for (int s = t; s < BATCH * 128; s += 256) t3[s] = 0.f;
    } else if (b < 1 + NCLS) {
        int cls = b - 1;
        __shared__ float su1[64], sv1[64];
        __shared__ float lu[128], lv[128], lw[128], lb[128];
        __shared__ float qA[256], qV[256], qW[256], qB[256];
        if (t < 64) {
            float a = 0.f, bb = 0.f;
            for (int c = 0; c < 32; ++c) {
                float w = W1[t * 32 + c];
                a  += w * W0[c];      // W0 is (32,1)
                bb += w * b0[c];
            }
            su1[t] = a; sv1[t] = bb;
        }
        __syncthreads();
        if (t < 128) {
            float a = 0.f, bb = 0.f, cc = 0.f;
            for (int j = 0; j < 64; ++j) {
                float w = W2[t * 64 + j];
                a  += w * su1[j];
                bb += w * sv1[j];
                cc += w * b1[j];
            }
            lu[t] = a; lv[t] = bb; lw[t] = cc; lb[t] = b2[t];
        }
        __syncthreads();
        int m = t & 127, h = t >> 7;
        const float* fw = fc_w + cls * 16384 + m;
        float A = 0.f, V = 0.f, Wt = 0.f, Bt = 0.f;
        #pragma unroll 16
        for (int o = h * 64; o < h * 64 + 64; ++o) {
            float wv = fw[o * 128];
            A  += wv * lu[o];
            V  += wv * lv[o];
            Wt += wv * lw[o];
            Bt += wv * lb[o];
        }
        qA[t] = A; qV[t] = V; qW[t] = Wt; qB[t] = Bt;
        __syncthreads();
        if (h == 0) {
            Sa[cls * 128 + m] = qA[m] + qA[128 + m];
            Sv[cls * 128 + m] = qV[m] + qV[128 + m];
            Sw[cls * 128 + m] = qW[m] + qW[128 + m];
            Sb[cls * 128 + m] = qB[m] + qB[128 + m];
        }
    } else if (b < 1 + NCLS + HIST_BLOCKS) {
        __shared__ int hA[128], hB[128];
        if (t < 128) { hA[t] = 0; hB[t] = 0; }
        __syncthreads();
        const int total = N1 + N2;
        const int stride = HIST_BLOCKS * 256;
        int hb = b - (1 + NCLS);
        for (int idx = hb * 256 + t; idx < total; idx += stride) {
            if (idx < N1) atomicAdd(&hA[p2[p1[idx]]], 1);
            else          atomicAdd(&hB[p2[idx - N1]], 1);
        }
        __syncthreads();
        hist[hb * 256 + t] = (t < 128) ? hA[t] : hB[t - 128];
    } else {
        int mb = b - (1 + NCLS + HIST_BLOCKS);
        int base = mb * MCHUNK;
        #pragma unroll
        for (int u = 0; u < MCHUNK / 256; ++u) {
            int i = base + u * 256 + t;
            if (i < IN_FEATURES) midx[i] = p2[p1[p0[i]]];
        }
    }
}

// k_t3: flat float4 decomposition of x (rows are not individually 16B
// aligned; the flat array is). 830 blocks x 8192 elems. Each block spans at
// most one row boundary -> per-wave private {2 rows x 128 bins} LDS
// histograms, selected per element. Batched loads (2x float4 + 8 midx) then
// 8 ds_add_f32 for ILP.
__global__ __launch_bounds__(256) void k_t3(
    const float* __restrict__ x, const int* __restrict__ midx,
    float* __restrict__ t3)
{
    __shared__ float hist[4 * 256];   // 4 waves x {sel(2) x 128 bins}
    int t = threadIdx.x;
    #pragma unroll
    for (int s = t; s < 1024; s += 256) hist[s] = 0.f;
    __syncthreads();

    int b = blockIdx.x;
    int f0 = b * (CF4 * 4);
    int row0 = f0 / IN_FEATURES;
    int rb = row0 * IN_FEATURES;
    float* hw = hist + (t >> 6) * 256;
    const float4* x4 = (const float4*)x;
    int base4 = b * CF4 + t;

    if (b != NT3B - 1) {
        for (int kk = 0; kk < 4; ++kk) {
            int fA = base4 + (2 * kk) * 256;
            int fB = base4 + (2 * kk + 1) * 256;
            float4 vA = x4[fA];
            float4 vB = x4[fB];
            int lA = fA * 4 - rb;
            int lB = fB * 4 - rb;
            int mi[8], sl[8];
            #pragma unroll
            for (int e = 0; e < 4; ++e) {
                int l = lA + e; int sg = (l >= IN_FEATURES);
                sl[e] = sg; mi[e] = midx[sg ? l - IN_FEATURES : l];
            }
            #pragma unroll
            for (int e = 0; e < 4; ++e) {
                int l = lB + e; int sg = (l >= IN_FEATURES);
                sl[4 + e] = sg; mi[4 + e] = midx[sg ? l - IN_FEATURES : l];
            }
            atomicAdd(&hw[sl[0] * 128 + mi[0]], vA.x);
            atomicAdd(&hw[sl[1] * 128 + mi[1]], vA.y);
            atomicAdd(&hw[sl[2] * 128 + mi[2]], vA.z);
            atomicAdd(&hw[sl[3] * 128 + mi[3]], vA.w);
            atomicAdd(&hw[sl[4] * 128 + mi[4]], vB.x);
            atomicAdd(&hw[sl[5] * 128 + mi[5]], vB.y);
            atomicAdd(&hw[sl[6] * 128 + mi[6]], vB.z);
            atomicAdd(&hw[sl[7] * 128 + mi[7]], vB.w);
        }
    } else {
        for (int kk = 0; kk < 8; ++kk) {
            int f4 = base4 + kk * 256;
            if (f4 < TOTF4) {
                float4 v = x4[f4];
                int l0 = f4 * 4 - rb;
                float vv[4] = {v.x, v.y, v.z, v.w};
                #pragma unroll
                for (int e = 0; e < 4; ++e) {
                    int l = l0 + e; int sg = (l >= IN_FEATURES);
                    atomicAdd(&hw[sg * 128 + midx[sg ? l - IN_FEATURES : l]], vv[e]);
                }
            }
        }
    }
    __syncthreads();
    if (t < 128) {
        float s0 = hist[t] + hist[256 + t] + hist[512 + t] + hist[768 + t];
        atomicAdd(&t3[row0 * 128 + t], s0);
        int bnd = rb + IN_FEATURES;
        int fend = f0 + CF4 * 4; if (fend > TOTF) fend = TOTF;
        if (row0 + 1 < BATCH && bnd < fend) {
            float s1 = hist[128 + t] + hist[384 + t] + hist[640 + t] + hist[896 + t];
            atomicAdd(&t3[(row0 + 1) * 128 + t], s1);
        }
    }
}

// k_final, grid = 20 blocks x 256. fc_w contraction already done in k_setup;
// this kernel only combines hist counts with Sv/Sw/Sb into the constant and
// dots Sa against t3. ~50 KB of reads per block.
__global__ __launch_bounds__(256) void k_final(
    const float* __restrict__ fc_b,
    const float* __restrict__ Sa, const float* __restrict__ Sv,
    const float* __restrict__ Sw, const float* __restrict__ Sb,
    const int* __restrict__ hist, const float* __restrict__ t3,
    float* __restrict__ out)
{
    __shared__ float sA[128], red[128], r2[256];
    __shared__ float st3[BATCH * 129];
    __shared__ float sconst;
    int t = threadIdx.x;
    int cls = blockIdx.x;

    if (t < 128) {
        int c2 = 0, cn2 = 0;
        #pragma unroll
        for (int hb = 0; hb < HIST_BLOCKS; ++hb) {
            c2  += hist[hb * 256 + t];
            cn2 += hist[hb * 256 + 128 + t];
        }
        sA[t]  = Sa[cls * 128 + t];
        red[t] = (float)c2 * Sv[cls * 128 + t]
               + (float)cn2 * Sw[cls * 128 + t]
               + Sb[cls * 128 + t];
    }
    for (int s = t; s < BATCH * 128; s += 256)
        st3[(s >> 7) * 129 + (s & 127)] = t3[s];
    __syncthreads();
    for (int s2 = 64; s2 > 0; s2 >>= 1) {
        if (t < s2) red[t] += red[t + s2];
        __syncthreads();
    }
    if (t == 0) sconst = red[0] + fc_b[cls];
    __syncthreads();

    // 32 rows x 8 octants of 16
    int n = t >> 3, oc = t & 7;
    const float* tr = st3 + n * 129 + oc * 16;
    const float* ar = sA + oc * 16;
    float s = 0.f;
    #pragma unroll
    for (int k = 0; k < 16; ++k) s += ar[k] * tr[k];
    r2[t] = s;
    __syncthreads();
    if (oc == 0) {
        float tot = sconst;
        #pragma unroll
        for (int k = 0; k < 8; ++k) tot += r2[t + k];
        out[n * NCLS + cls] = tot;
    }
}

extern "C" void kernel_launch(void* const* d_in, const int* in_sizes, int n_in,
                              void* d_out, int out_size, void* d_ws, size_t ws_size,
                              hipStream_t stream)
{
    const float* x    = (const float*)d_in[0];
    const float* W0   = (const float*)d_in[1];
    const float* b0   = (const float*)d_in[2];
    const float* W1   = (const float*)d_in[3];
    const float* b1   = (const float*)d_in[4];
    const float* W2   = (const float*)d_in[5];
    const float* b2   = (const float*)d_in[6];
    const float* fc_w = (const float*)d_in[7];
    const float* fc_b = (const float*)d_in[8];
    const int*   p0   = (const int*)d_in[9];
    const int*   p1   = (const int*)d_in[10];
    const int*   p2   = (const int*)d_in[11];

    char* ws = (char*)d_ws;
    float* t3   = (float*)(ws + 0);
    int*   hist = (int*)(ws + 16384);
    float* Sa   = (float*)(ws + 49152);
    float* Sv   = (float*)(ws + 59392);
    float* Sw   = (float*)(ws + 69632);
    float* Sb   = (float*)(ws + 79872);
    int*   midx = (int*)(ws + 90112);

    k_setup<<<1 + NCLS + HIST_BLOCKS + MBLOCKS, 256, 0, stream>>>(
        W0, b0, W1, b1, W2, b2, fc_w, p0, p1, p2, t3, hist, Sa, Sv, Sw, Sb, midx);
    k_t3<<<NT3B, 256, 0, stream>>>(x, midx, t3);
    k_final<<<NCLS, 256, 0, stream>>>(fc_b, Sa, Sv, Sw, Sb, hist, t3,
                                      (float*)d_out);
}